// Round 3
// baseline (427.122 us; speedup 1.0000x reference)
//
#include <hip/hip_runtime.h>

// out[b,s,f] = sx[b,s] * sk[f] * sum_d qx[b,s,d] * qk[d,f]
// Exact int32 accumulation via v_mfma_i32_32x32x32_i8 (R3: was 16x16x64;
// 32x32 pipe is ~12% faster: 4404 vs 3944 TOPS, half the issue slots).
//
// Global fragment-tiled layouts (R2 win, generalized to 32-row tiles):
//   T[tile32][kslice16B][row32][16B]  -> staging is 1KB-contiguous per
//   wave-instr AND ds_read_b128 fragment reads are base+lane*16
//   (conflict-free; R2 measured SQ_LDS_BANK_CONFLICT == 0).
// R3 quant_act: 4 consecutive rows/block so the 16B-per-row tiled-layout
// chunks complete full 64B lines inside one block (one XCD's L2) -> no
// HBM write amplification (R2 suspect: +4x on At writes).

#define M_DIM 8192
#define K_DIM 4096
#define N_DIM 4096

typedef int v4i __attribute__((ext_vector_type(4)));
typedef int v16i __attribute__((ext_vector_type(16)));
typedef __attribute__((address_space(3))) void lds_void_t;
typedef const __attribute__((address_space(1))) void g_void_t;

// ---------------- activation quantization: 4 rows/block, 1 wave/row ----------------
__global__ void quant_act(const float* __restrict__ X,
                          signed char* __restrict__ At,
                          float* __restrict__ sx) {
  const int row0 = blockIdx.x * 4;
  const int t = threadIdx.x;  // 256
  const int lane = t & 63;
  const int w = t >> 6;  // wave = row offset
  const int row = row0 + w;
  const float* xr = X + (size_t)row * K_DIM;

  float4 v[16];
  float am = 0.f;
#pragma unroll
  for (int c = 0; c < 16; ++c) {
    v[c] = ((const float4*)xr)[c * 64 + lane];  // 1KB/wave-instr coalesced
    am = fmaxf(am, fmaxf(fmaxf(fabsf(v[c].x), fabsf(v[c].y)),
                         fmaxf(fabsf(v[c].z), fabsf(v[c].w))));
  }
#pragma unroll
  for (int off = 32; off > 0; off >>= 1)
    am = fmaxf(am, __shfl_xor(am, off));  // all lanes get row amax
  const float scale = fmaxf(am, 1e-6f) / 127.0f;  // matches ref
  if (lane == 0) sx[row] = scale;
  const float inv = 1.0f / scale;

  __shared__ unsigned int shuf[4096];  // 16KB: [row4][1024 packed dwords]
#pragma unroll
  for (int c = 0; c < 16; ++c) {
    int q0 = (int)fminf(fmaxf(rintf(v[c].x * inv), -127.f), 127.f);
    int q1 = (int)fminf(fmaxf(rintf(v[c].y * inv), -127.f), 127.f);
    int q2 = (int)fminf(fmaxf(rintf(v[c].z * inv), -127.f), 127.f);
    int q3 = (int)fminf(fmaxf(rintf(v[c].w * inv), -127.f), 127.f);
    shuf[w * 1024 + c * 64 + lane] =
        (q0 & 255) | ((q1 & 255) << 8) | ((q2 & 255) << 16) | (q3 << 24);
  }
  __syncthreads();
  // chunk c: ks = c>>2, r4 = c&3; lanes 0..3 complete one 64B line
  const size_t tbase = (size_t)(row0 >> 5) * 131072;
  const int rbase = row0 & 31;
#pragma unroll
  for (int i = 0; i < 4; ++i) {
    const int c = i * 256 + t;
    const int ks = c >> 2;
    const int r4 = c & 3;
    v4i val = *(const v4i*)&shuf[r4 * 1024 + ks * 4];
    *(v4i*)(At + tbase + ks * 512 + (rbase + r4) * 16) = val;
  }
}

// ---------------- weight column-amax: 512 partial blocks + combine ----------------
__global__ void wk_amax_part(const float* __restrict__ Kmat, float* __restrict__ part) {
  const int f = blockIdx.x * 256 + threadIdx.x;
  const float* p = Kmat + (size_t)(blockIdx.y * 128) * N_DIM + f;
  float a0 = 0.f, a1 = 0.f, a2 = 0.f, a3 = 0.f;
#pragma unroll 4
  for (int i = 0; i < 32; ++i) {
    a0 = fmaxf(a0, fabsf(p[0 * N_DIM]));
    a1 = fmaxf(a1, fabsf(p[1 * N_DIM]));
    a2 = fmaxf(a2, fabsf(p[2 * N_DIM]));
    a3 = fmaxf(a3, fabsf(p[3 * N_DIM]));
    p += 4 * N_DIM;
  }
  part[(size_t)blockIdx.y * N_DIM + f] = fmaxf(fmaxf(a0, a1), fmaxf(a2, a3));
}

__global__ void wk_amax_comb(const float* __restrict__ part,
                             float* __restrict__ sk, float* __restrict__ skinv) {
  const int f = blockIdx.x * 256 + threadIdx.x;
  float am = 0.f;
#pragma unroll
  for (int s = 0; s < 32; ++s) am = fmaxf(am, part[(size_t)s * N_DIM + f]);
  float scale = fmaxf(am, 1e-6f) / 127.0f;
  sk[f] = scale;
  skinv[f] = 1.0f / scale;
}

// ---------------- weight quant + transpose into Bt[nt32][ks][r32][16B] ----------------
__global__ void wk_quant(const float* __restrict__ Kmat,
                         const float* __restrict__ skinv,
                         signed char* __restrict__ Bt) {
  const int f0 = (blockIdx.x & 63) * 64;
  const int d0 = (blockIdx.x >> 6) * 64;
  const int t = threadIdx.x;
  const int fl = t & 63;
  const int dl0 = t >> 6;  // 0..3
  __shared__ __align__(16) signed char tile[64 * 80];  // row stride 80 (16-aligned)
  const float inv = skinv[f0 + fl];
#pragma unroll
  for (int c = 0; c < 16; ++c) {
    const int dl = c * 4 + dl0;
    float vv = Kmat[(size_t)(d0 + dl) * N_DIM + f0 + fl];  // coalesced
    float q = fminf(fmaxf(rintf(vv * inv), -127.f), 127.f);
    tile[fl * 80 + dl] = (signed char)(int)q;
  }
  __syncthreads();
  // one 16B chunk per thread: frow = t>>2 (0..63), ksl = t&3
  const int frow = t >> 2;
  const int ksl = t & 3;
  v4i w = *(const v4i*)&tile[frow * 80 + ksl * 16];
  const int f = f0 + frow;
  signed char* dst =
      Bt + (size_t)(f >> 5) * 131072 + ((d0 >> 4) + ksl) * 512 + (f & 31) * 16;
  *(v4i*)dst = w;  // f consecutive within block -> 64B lines complete in-block
}

// ---------------- int8 GEMM: 128x128 tile, BK=128, 4 waves, 32x32x32 i8 MFMA ----------------
__global__ __launch_bounds__(256, 2) void gemm_i8(
    const signed char* __restrict__ At, const signed char* __restrict__ Bt,
    const float* __restrict__ sx, const float* __restrict__ sk,
    float* __restrict__ C) {
  const int n0 = blockIdx.x * 128;
  const int m0 = blockIdx.y * 128;
  const int t = threadIdx.x;
  const int lane = t & 63;
  const int wave = t >> 6;
  const int wm = (wave >> 1) * 64;  // wave's 64x64 sub-tile
  const int wn = (wave & 1) * 64;

  // LDS mirrors fragment-tiled order: [tile32_local 4][ks8][row32][16B] = 16KB each
  __shared__ __align__(16) signed char lds[32768];
  signed char* lA = lds;
  signed char* lB = lds + 16384;

  v16i acc[2][2];
#pragma unroll
  for (int i = 0; i < 2; ++i)
#pragma unroll
    for (int j = 0; j < 2; ++j)
#pragma unroll
      for (int e = 0; e < 16; ++e) acc[i][j][e] = 0;

  const signed char* Abase = At + (size_t)(m0 >> 5) * 131072;
  const signed char* Bbase = Bt + (size_t)(n0 >> 5) * 131072;

  // fragment bases: addr = tile32_local*4096 + s*1024 + lane*16 (contiguous)
  const int la = (wave >> 1) * 2 * 4096 + lane * 16;
  const int lb = (wave & 1) * 2 * 4096 + lane * 16;

  for (int kb = 0; kb < K_DIM; kb += 128) {
    const int kofs = kb * 32;  // (kb/16)*512 bytes into each tile32
    // stage 16KB A + 16KB B: every wave-instr reads 1KB contiguous global
#pragma unroll
    for (int j = 0; j < 4; ++j) {
      const int c = j * 256 + t;
      const int tl = c >> 8;       // tile32_local 0..3
      const int inner = c & 255;   // ks_l*32 + row
      __builtin_amdgcn_global_load_lds(
          (g_void_t*)(Abase + (size_t)tl * 131072 + kofs + inner * 16),
          (lds_void_t*)(lA + c * 16), 16, 0, 0);
      __builtin_amdgcn_global_load_lds(
          (g_void_t*)(Bbase + (size_t)tl * 131072 + kofs + inner * 16),
          (lds_void_t*)(lB + c * 16), 16, 0, 0);
    }
    __syncthreads();
#pragma unroll
    for (int s = 0; s < 4; ++s) {  // four K=32 steps per staging round
      v4i af[2], bf[2];
#pragma unroll
      for (int i = 0; i < 2; ++i) af[i] = *(const v4i*)(lA + la + i * 4096 + s * 1024);
#pragma unroll
      for (int i = 0; i < 2; ++i) bf[i] = *(const v4i*)(lB + lb + i * 4096 + s * 1024);
#pragma unroll
      for (int mi = 0; mi < 2; ++mi)
#pragma unroll
        for (int ni = 0; ni < 2; ++ni)
          acc[mi][ni] =
              __builtin_amdgcn_mfma_i32_32x32x32_i8(af[mi], bf[ni], acc[mi][ni], 0, 0, 0);
    }
    __syncthreads();
  }

  // epilogue: 32x32 C/D layout col=lane&31, row=(reg&3)+8*(reg>>2)+4*(lane>>5)
  const int lcol = lane & 31;
  const int lhi = (lane >> 5) * 4;
#pragma unroll
  for (int mi = 0; mi < 2; ++mi) {
#pragma unroll
    for (int ni = 0; ni < 2; ++ni) {
      const int gn = n0 + wn + ni * 32 + lcol;
      const float skv = sk[gn];
#pragma unroll
      for (int r = 0; r < 16; ++r) {
        const int rowl = (r & 3) + 8 * (r >> 2) + lhi;
        const int gm = m0 + wm + mi * 32 + rowl;
        C[(size_t)gm * N_DIM + gn] = (float)acc[mi][ni][r] * sx[gm] * skv;
      }
    }
  }
}

// ---------------- launch ----------------
extern "C" void kernel_launch(void* const* d_in, const int* in_sizes, int n_in,
                              void* d_out, int out_size, void* d_ws, size_t ws_size,
                              hipStream_t stream) {
  const float* X = (const float*)d_in[0];  // [4,2048,4096] fp32
  const float* W = (const float*)d_in[1];  // [4096,4096] fp32
  float* out = (float*)d_out;              // [4,2048,4096] fp32
  char* ws = (char*)d_ws;

  signed char* At = (signed char*)ws;                       // 32 MB  tiled A (256 tiles)
  signed char* Bt = (signed char*)(ws + 33554432);          // 16 MB  tiled B (128 tiles)
  float* sx = (float*)(ws + 50331648);                      // 32 KB
  float* sk = (float*)(ws + 50364416);                      // 16 KB
  float* skinv = (float*)(ws + 50380800);                   // 16 KB
  float* part = (float*)(ws + 50397184);                    // 512 KB

  quant_act<<<M_DIM / 4, 256, 0, stream>>>(X, At, sx);
  wk_amax_part<<<dim3(16, 32), 256, 0, stream>>>(W, part);
  wk_amax_comb<<<16, 256, 0, stream>>>(part, sk, skinv);
  wk_quant<<<4096, 256, 0, stream>>>(W, skinv, Bt);
  gemm_i8<<<dim3(N_DIM / 128, M_DIM / 128), 256, 0, stream>>>(At, Bt, sx, sk, out);
}